// Round 1
// baseline (353.007 us; speedup 1.0000x reference)
//
#include <hip/hip_runtime.h>

// GRU (Keras reset_after=True, relu activation) fused kernel for MI355X.
// One block (256 threads, 4 waves) per batch row. Per 16-step chunk:
//   Phase A: X[16][192] = inputs[b, 16c:16c+16, :] @ W + b0 via bf16x3 MFMA
//            (hi/lo split for ~fp32 accuracy), W fragments register-resident.
//   Phase B: 16 sequential GRU steps, fp32 vector. U column per thread in
//            registers (64 VGPR), h broadcast from LDS.
// Epilogue: h @ W1 -> relu -> @ W2 -> softmax, per block.

#define B_SZ   512
#define T_SZ   512
#define F_SZ   128
#define UN     64
#define G3     192          // 3*UN
#define CHUNK  16
#define NCHUNK (T_SZ / CHUNK)
#define NCLS   10

using short8 = __attribute__((ext_vector_type(8))) short;
using f32x4  = __attribute__((ext_vector_type(4))) float;

__device__ __forceinline__ unsigned short f2bf_rn(float f) {
    unsigned int u = __float_as_uint(f);
    unsigned int r = u + 0x7FFFu + ((u >> 16) & 1u);
    return (unsigned short)(r >> 16);
}
__device__ __forceinline__ float bf2f(unsigned short s) {
    return __uint_as_float(((unsigned int)s) << 16);
}
__device__ __forceinline__ float sigmoidf_(float x) {
    return 1.0f / (1.0f + __expf(-x));
}

__global__ __launch_bounds__(256, 2)
void gru_fused_kernel(const float* __restrict__ inp,   // [512,512,128]
                      const float* __restrict__ W,     // [128,192]
                      const float* __restrict__ U,     // [64,192]
                      const float* __restrict__ bias,  // [2,192]
                      const float* __restrict__ W1,    // [64,64]
                      const float* __restrict__ b1,    // [64]
                      const float* __restrict__ W2,    // [64,10]
                      const float* __restrict__ b2,    // [10]
                      float* __restrict__ out)         // [512,10]
{
    const int brow = blockIdx.x;
    const int tid  = threadIdx.x;
    const int wave = tid >> 6;
    const int lane = tid & 63;
    const int l15  = lane & 15;
    const int l4   = lane >> 4;   // 0..3

    __shared__ __align__(16) float Xb[CHUNK][196];  // x_proj chunk (+b0), padded
    __shared__ __align__(16) float hbuf[UN];
    __shared__ float recbuf[G3];
    __shared__ float scratch[UN];

    // ---- W fragments: this wave owns col-tiles 3*wave..3*wave+2.
    // B-operand layout (16x16x32): col = lane&15, k = 8*(lane>>4)+e.
    short8 wfh[3][4], wfl[3][4];
    #pragma unroll
    for (int c = 0; c < 3; ++c) {
        const int col = 16 * (wave * 3 + c) + l15;
        #pragma unroll
        for (int kt = 0; kt < 4; ++kt) {
            const int kb = 32 * kt + 8 * l4;
            #pragma unroll
            for (int e = 0; e < 8; ++e) {
                float w = W[(kb + e) * G3 + col];
                unsigned short h = f2bf_rn(w);
                unsigned short l = f2bf_rn(w - bf2f(h));
                wfh[c][kt][e] = (short)h;
                wfl[c][kt][e] = (short)l;
            }
        }
    }
    float b0c[3];
    #pragma unroll
    for (int c = 0; c < 3; ++c) b0c[c] = bias[16 * (wave * 3 + c) + l15];

    // ---- U column (threads 0..191) register-resident + recurrent bias
    float ucol[UN];
    float brj = 0.0f;
    if (tid < G3) {
        #pragma unroll
        for (int k = 0; k < UN; ++k) ucol[k] = U[k * G3 + tid];
        brj = bias[G3 + tid];
    }

    if (tid < UN) hbuf[tid] = 0.0f;
    __syncthreads();

    const float* inrow = inp + (size_t)brow * T_SZ * F_SZ;

    for (int c = 0; c < NCHUNK; ++c) {
        // ---------- Phase A: X = in_chunk @ W  (bf16x3 MFMA) ----------
        f32x4 acc[3];
        #pragma unroll
        for (int ct = 0; ct < 3; ++ct) acc[ct] = (f32x4){0.f, 0.f, 0.f, 0.f};

        #pragma unroll
        for (int kt = 0; kt < 4; ++kt) {
            // A-operand layout: row(t) = lane&15, k = 8*(lane>>4)+e
            const float* ap = inrow + (size_t)(c * CHUNK + l15) * F_SZ + 32 * kt + 8 * l4;
            f32x4 v0 = *(const f32x4*)(ap);
            f32x4 v1 = *(const f32x4*)(ap + 4);
            float av[8] = {v0[0], v0[1], v0[2], v0[3], v1[0], v1[1], v1[2], v1[3]};
            short8 ah, al;
            #pragma unroll
            for (int e = 0; e < 8; ++e) {
                unsigned short h = f2bf_rn(av[e]);
                unsigned short l = f2bf_rn(av[e] - bf2f(h));
                ah[e] = (short)h; al[e] = (short)l;
            }
            #pragma unroll
            for (int ct = 0; ct < 3; ++ct) {
                acc[ct] = __builtin_amdgcn_mfma_f32_16x16x32_bf16(ah, wfh[ct][kt], acc[ct], 0, 0, 0);
                acc[ct] = __builtin_amdgcn_mfma_f32_16x16x32_bf16(al, wfh[ct][kt], acc[ct], 0, 0, 0);
                acc[ct] = __builtin_amdgcn_mfma_f32_16x16x32_bf16(ah, wfl[ct][kt], acc[ct], 0, 0, 0);
            }
        }
        // D layout: col = lane&15, row = 4*(lane>>4)+r. Previous Phase B's
        // final barrier guarantees Xb is free to overwrite.
        #pragma unroll
        for (int ct = 0; ct < 3; ++ct) {
            const int col = 16 * (wave * 3 + ct) + l15;
            #pragma unroll
            for (int r = 0; r < 4; ++r)
                Xb[4 * l4 + r][col] = acc[ct][r] + b0c[ct];
        }
        __syncthreads();

        // ---------- Phase B: 16 sequential GRU steps ----------
        for (int s = 0; s < CHUNK; ++s) {
            if (tid < G3) {
                float a0 = 0.f, a1 = 0.f, a2 = 0.f, a3 = 0.f;
                const f32x4* h4 = (const f32x4*)hbuf;
                #pragma unroll
                for (int kk = 0; kk < UN / 4; ++kk) {
                    f32x4 hv = h4[kk];          // broadcast read
                    a0 = fmaf(hv[0], ucol[4 * kk + 0], a0);
                    a1 = fmaf(hv[1], ucol[4 * kk + 1], a1);
                    a2 = fmaf(hv[2], ucol[4 * kk + 2], a2);
                    a3 = fmaf(hv[3], ucol[4 * kk + 3], a3);
                }
                recbuf[tid] = (a0 + a1) + (a2 + a3) + brj;
            }
            __syncthreads();
            if (tid < UN) {
                float xz = Xb[s][tid], xr = Xb[s][UN + tid], xh = Xb[s][2 * UN + tid];
                float rz = recbuf[tid], rr = recbuf[UN + tid], rh = recbuf[2 * UN + tid];
                float z  = sigmoidf_(xz + rz);
                float r  = sigmoidf_(xr + rr);
                float hh = fmaxf(fmaf(r, rh, xh), 0.0f);
                float h  = hbuf[tid];
                hbuf[tid] = fmaf(z, h - hh, hh);   // z*h + (1-z)*hh
            }
            __syncthreads();
        }
    }

    // ---------- head: relu(h@W1+b1) @ W2 + b2 -> softmax ----------
    if (tid < UN) {
        float a = b1[tid];
        #pragma unroll
        for (int k = 0; k < UN; ++k) a = fmaf(hbuf[k], W1[k * UN + tid], a);
        scratch[tid] = fmaxf(a, 0.0f);
    }
    __syncthreads();
    if (tid < NCLS) {
        float a = b2[tid];
        #pragma unroll
        for (int k = 0; k < UN; ++k) a = fmaf(scratch[k], W2[k * NCLS + tid], a);
        recbuf[tid] = a;
    }
    __syncthreads();
    if (tid < NCLS) {
        float m = recbuf[0];
        #pragma unroll
        for (int k = 1; k < NCLS; ++k) m = fmaxf(m, recbuf[k]);
        float ssum = 0.0f;
        #pragma unroll
        for (int k = 0; k < NCLS; ++k) ssum += __expf(recbuf[k] - m);
        out[brow * NCLS + tid] = __expf(recbuf[tid] - m) / ssum;
    }
}

extern "C" void kernel_launch(void* const* d_in, const int* in_sizes, int n_in,
                              void* d_out, int out_size, void* d_ws, size_t ws_size,
                              hipStream_t stream) {
    const float* inp  = (const float*)d_in[0];
    const float* W    = (const float*)d_in[1];
    const float* U    = (const float*)d_in[2];
    const float* bias = (const float*)d_in[3];
    const float* W1   = (const float*)d_in[4];
    const float* b1   = (const float*)d_in[5];
    const float* W2   = (const float*)d_in[6];
    const float* b2   = (const float*)d_in[7];
    float* out = (float*)d_out;

    gru_fused_kernel<<<B_SZ, 256, 0, stream>>>(inp, W, U, bias, W1, b1, W2, b2, out);
}